// Round 1
// baseline (8830.605 us; speedup 1.0000x reference)
//
#include <hip/hip_runtime.h>

typedef unsigned short u16;
typedef unsigned int   u32;

typedef __attribute__((ext_vector_type(8)))  short bf16x8;
typedef __attribute__((ext_vector_type(4)))  float f32x4;
typedef __attribute__((ext_vector_type(16))) float f32x16;

#define B_  32
#define S_  1024
#define NH_ 512
#define G4_ 2048   // 4*NH
#define SCAN_NWG 64

__device__ __forceinline__ float bf2f(u16 h) {
    return __uint_as_float(((u32)h) << 16);
}
__device__ __forceinline__ u16 f2bf(float f) {
    u32 u = __float_as_uint(f);
    return (u16)((u + 0x7fffu + ((u >> 16) & 1u)) >> 16);
}
__device__ __forceinline__ float fsig(float x) {
    return 1.0f / (1.0f + __expf(-x));
}
__device__ __forceinline__ float ftanh(float x) {
    // tanh(x) = 1 - 2/(exp(2x)+1); saturates correctly for |x| large
    return 1.0f - 2.0f / (__expf(2.0f * x) + 1.0f);
}

// ---------------- fp32 -> bf16 elementwise convert (vectorized x4) ----------
__global__ void cvt_bf16_kernel(const float* __restrict__ in, u16* __restrict__ out, int n4) {
    int i = blockIdx.x * blockDim.x + threadIdx.x;
    if (i >= n4) return;
    f32x4 v = ((const f32x4*)in)[i];
    unsigned long long pk =
        (unsigned long long)f2bf(v[0]) |
        ((unsigned long long)f2bf(v[1]) << 16) |
        ((unsigned long long)f2bf(v[2]) << 32) |
        ((unsigned long long)f2bf(v[3]) << 48);
    ((unsigned long long*)out)[i] = pk;
}

// ---------------- fp32 [R][C] -> bf16 [C][R] transpose-convert --------------
__global__ void transpose_cvt_kernel(const float* __restrict__ in, u16* __restrict__ out,
                                     int R, int C) {
    __shared__ float tile[32][33];
    int bx = blockIdx.x, by = blockIdx.y;
    int tx = threadIdx.x & 31, ty = threadIdx.x >> 5;
    #pragma unroll
    for (int i = 0; i < 4; i++) {
        int r = by * 32 + ty + i * 8;
        tile[ty + i * 8][tx] = in[(size_t)r * C + bx * 32 + tx];
    }
    __syncthreads();
    #pragma unroll
    for (int i = 0; i < 4; i++) {
        int c = bx * 32 + ty + i * 8;
        out[(size_t)c * R + by * 32 + tx] = f2bf(tile[tx][ty + i * 8]);
    }
}

// ---------------- generic bf16 MFMA GEMM: C = A @ BT^T + bias ---------------
// A [M][K] bf16 row-major, BT [N][K] bf16 (i.e. B transposed), bias [N] f32.
// out_bf16: 1 -> store bf16, 0 -> store f32. BM=BN=128, BK=32, 256 threads.
__global__ __launch_bounds__(256) void gemm_bf16_kernel(
    const u16* __restrict__ A, const u16* __restrict__ BT,
    const float* __restrict__ bias, void* __restrict__ Cp,
    int M, int N, int K, int out_bf16)
{
    __shared__ u16 Al[128][40];   // +8 bf16 pad: rows stay 16B-aligned, 2-way banks
    __shared__ u16 Bl[128][40];
    int nbm = M >> 7;
    int bm = blockIdx.x % nbm, bn = blockIdx.x / nbm;
    int tid = threadIdx.x, lane = tid & 63, wave = tid >> 6;
    int wr = wave >> 1, wc = wave & 1;       // 2x2 wave grid, 64x64 per wave
    f32x4 acc[4][4];
    #pragma unroll
    for (int i = 0; i < 4; i++)
        #pragma unroll
        for (int j = 0; j < 4; j++)
            acc[i][j] = (f32x4){0.f, 0.f, 0.f, 0.f};
    int fr  = lane & 15;          // fragment row/col within 16
    int kof = (lane >> 4) << 3;   // k offset 0/8/16/24

    for (int k0 = 0; k0 < K; k0 += 32) {
        __syncthreads();
        #pragma unroll
        for (int i = 0; i < 2; i++) {
            int chunk = i * 256 + tid;            // 512 chunks of 8 bf16
            int r = chunk >> 2, c = (chunk & 3) << 3;
            *(bf16x8*)&Al[r][c] = *(const bf16x8*)&A[(size_t)(bm * 128 + r) * K + k0 + c];
            *(bf16x8*)&Bl[r][c] = *(const bf16x8*)&BT[(size_t)(bn * 128 + r) * K + k0 + c];
        }
        __syncthreads();
        bf16x8 af[4], bfr[4];
        #pragma unroll
        for (int mi = 0; mi < 4; mi++)
            af[mi] = *(const bf16x8*)&Al[wr * 64 + mi * 16 + fr][kof];
        #pragma unroll
        for (int ni = 0; ni < 4; ni++)
            bfr[ni] = *(const bf16x8*)&Bl[wc * 64 + ni * 16 + fr][kof];
        #pragma unroll
        for (int mi = 0; mi < 4; mi++)
            #pragma unroll
            for (int ni = 0; ni < 4; ni++)
                acc[mi][ni] = __builtin_amdgcn_mfma_f32_16x16x32_bf16(af[mi], bfr[ni], acc[mi][ni], 0, 0, 0);
    }
    // epilogue: D col = lane&15, row = (lane>>4)*4 + reg   [m89-verified]
    int rq = lane >> 4;
    #pragma unroll
    for (int mi = 0; mi < 4; mi++) {
        #pragma unroll
        for (int ni = 0; ni < 4; ni++) {
            int n = bn * 128 + wc * 64 + ni * 16 + fr;
            float bv = bias ? bias[n] : 0.f;
            #pragma unroll
            for (int r = 0; r < 4; r++) {
                int m = bm * 128 + wr * 64 + mi * 16 + rq * 4 + r;
                float v = acc[mi][ni][r] + bv;
                if (out_bf16) ((u16*)Cp)[(size_t)m * N + n] = f2bf(v);
                else          ((float*)Cp)[(size_t)m * N + n] = v;
            }
        }
    }
}

// ---------------- LSTM scan: 64 persistent WGs x 1 wave ---------------------
// WG g owns hidden units [g*8, g*8+8) for ALL 32 batches; its 32 gate columns
// are {gate*512 + g*8 + u}. U fragments live in registers for the whole scan.
// One agent-scope barrier per timestep; h double-buffered in global (bf16).
__device__ __forceinline__ void grid_barrier(u32* cnt, u32 target) {
    __threadfence();                       // release: flush this XCD's L2
    if (threadIdx.x == 0) {
        __hip_atomic_fetch_add(cnt, 1u, __ATOMIC_RELEASE, __HIP_MEMORY_SCOPE_AGENT);
        while (__hip_atomic_load(cnt, __ATOMIC_ACQUIRE, __HIP_MEMORY_SCOPE_AGENT) < target)
            __builtin_amdgcn_s_sleep(1);
    }
    __threadfence();                       // acquire: invalidate stale L1/L2
    __syncthreads();
}

__global__ __launch_bounds__(64) void lstm_scan_kernel(
    const u16* __restrict__ xw,    // [B][S][4H] bf16 (xW + hid_bias)
    const u16* __restrict__ UT,    // [4H][NH] bf16 (U transposed)
    u16* __restrict__ hseq,        // [B][S][NH] bf16
    u16* __restrict__ hbuf,        // [2][B][NH] bf16
    u32* cnt)
{
    __shared__ u16 h_lds[32][520];        // [batch][k], +8 pad (16B-aligned rows)
    __shared__ float gates_lds[32][32];   // [batch][local col]
    int wg = blockIdx.x, lane = threadIdx.x;
    int col = lane & 31, half = lane >> 5;
    int u_loc = col >> 2, g_loc = col & 3;
    int ucol = g_loc * 512 + wg * 8 + u_loc;   // global gate column

    // persistent B-fragments: 32 x mfma_32x32x16, B lane layout col=l&31, k=(l>>5)*8+j
    bf16x8 ufrag[32];
    #pragma unroll
    for (int kk = 0; kk < 32; kk++)
        ufrag[kk] = *(const bf16x8*)&UT[(size_t)ucol * 512 + kk * 16 + half * 8];

    float cst[4] = {0.f, 0.f, 0.f, 0.f};

    // zero our slice of h0
    #pragma unroll
    for (int i = 0; i < 4; i++) {
        int p = i * 64 + lane;
        hbuf[(p >> 3) * 512 + wg * 8 + (p & 7)] = 0;
    }
    grid_barrier(cnt, SCAN_NWG);

    for (int t = 0; t < 1024; t++) {
        // prefetch xw for this step (used in epilogue; hides under staging+MFMA)
        u16 xwu[16];
        #pragma unroll
        for (int r = 0; r < 16; r++) {
            int b = (r & 3) + ((r >> 2) << 3) + (half << 2);   // D-row mapping
            xwu[r] = xw[((size_t)b * S_ + t) * G4_ + ucol];
        }
        // stage h [32][512] bf16 into LDS (broadcast read from L2/L3)
        const u16* hsrc = hbuf + ((t & 1) << 14);
        #pragma unroll
        for (int i = 0; i < 32; i++)
            *(bf16x8*)&h_lds[i][lane << 3] = *(const bf16x8*)&hsrc[i * 512 + (lane << 3)];
        __syncthreads();

        // gates[32 batches][32 cols] = h @ Uslice ; A row = batch = lane&31
        f32x16 acc = {0,0,0,0, 0,0,0,0, 0,0,0,0, 0,0,0,0};
        #pragma unroll
        for (int kk = 0; kk < 32; kk++) {
            bf16x8 af = *(const bf16x8*)&h_lds[col][kk * 16 + half * 8];
            acc = __builtin_amdgcn_mfma_f32_32x32x16_bf16(af, ufrag[kk], acc, 0, 0, 0);
        }
        // D layout: col = lane&31, row = (reg&3) + 8*(reg>>2) + 4*(lane>>5)
        #pragma unroll
        for (int r = 0; r < 16; r++) {
            int b = (r & 3) + ((r >> 2) << 3) + (half << 2);
            gates_lds[b][col] = acc[r] + bf2f(xwu[r]);
        }
        __syncthreads();

        // elementwise LSTM cell update; each lane owns 4 (batch,unit) pairs
        #pragma unroll
        for (int i = 0; i < 4; i++) {
            int p = (i << 6) + lane, b = p >> 3, u = p & 7;
            f32x4 g4 = *(const f32x4*)&gates_lds[b][u << 2];   // i,f,g,o
            float si = fsig(g4[0]), sf = fsig(g4[1]);
            float sg = ftanh(g4[2]), so = fsig(g4[3]);
            float c = sf * cst[i] + si * sg;
            cst[i] = c;
            float h = so * ftanh(c);
            u16 hb = f2bf(h);
            int j = (wg << 3) + u;
            hseq[((size_t)b * S_ + t) * NH_ + j] = hb;
            hbuf[(((t + 1) & 1) << 14) + b * 512 + j] = hb;
        }
        __syncthreads();
        if (t < 1023) grid_barrier(cnt, (u32)SCAN_NWG * (t + 2));
    }
}

extern "C" void kernel_launch(void* const* d_in, const int* in_sizes, int n_in,
                              void* d_out, int out_size, void* d_ws, size_t ws_size,
                              hipStream_t stream) {
    const float* x        = (const float*)d_in[0];
    const float* W        = (const float*)d_in[1];
    const float* U        = (const float*)d_in[2];
    const float* hid_bias = (const float*)d_in[3];
    const float* V        = (const float*)d_in[4];
    const float* out_bias = (const float*)d_in[5];

    char* ws = (char*)d_ws;
    size_t off = 0;
    auto carve = [&](size_t bytes) -> void* {
        void* p = ws + off;
        off += (bytes + 255) & ~(size_t)255;
        return p;
    };
    u16* xw   = (u16*)carve((size_t)B_ * S_ * G4_ * 2);   // 128 MB
    u16* xbf  = (u16*)carve((size_t)B_ * S_ * NH_ * 2);   //  32 MB
    u16* hseq = (u16*)carve((size_t)B_ * S_ * NH_ * 2);   //  32 MB
    u16* WT   = (u16*)carve((size_t)G4_ * NH_ * 2);       //   2 MB
    u16* UT   = (u16*)carve((size_t)G4_ * NH_ * 2);       //   2 MB
    u16* VT   = (u16*)carve((size_t)NH_ * NH_ * 2);       // 512 KB
    u16* hbuf = (u16*)carve((size_t)2 * B_ * NH_ * 2);    //  64 KB
    u32* cnt  = (u32*)carve(256);

    hipMemsetAsync(cnt, 0, 256, stream);

    int n4 = B_ * S_ * NH_ / 4;
    cvt_bf16_kernel<<<(n4 + 255) / 256, 256, 0, stream>>>(x, xbf, n4);
    transpose_cvt_kernel<<<dim3(G4_ / 32, NH_ / 32), 256, 0, stream>>>(W, WT, NH_, G4_);
    transpose_cvt_kernel<<<dim3(G4_ / 32, NH_ / 32), 256, 0, stream>>>(U, UT, NH_, G4_);
    transpose_cvt_kernel<<<dim3(NH_ / 32, NH_ / 32), 256, 0, stream>>>(V, VT, NH_, NH_);

    // xW = x @ W + hid_bias  -> bf16 [32768][2048]
    gemm_bf16_kernel<<<4096, 256, 0, stream>>>(xbf, WT, hid_bias, xw,
                                               B_ * S_, G4_, NH_, 1);
    // sequential LSTM scan
    lstm_scan_kernel<<<SCAN_NWG, 64, 0, stream>>>(xw, UT, hseq, hbuf, cnt);
    // out = hseq @ V + out_bias -> f32 [32768][512]
    gemm_bf16_kernel<<<1024, 256, 0, stream>>>(hseq, VT, out_bias, d_out,
                                               B_ * S_, NH_, NH_, 0);
}

// Round 2
// 5084.774 us; speedup vs baseline: 1.7367x; 1.7367x over previous
//
#include <hip/hip_runtime.h>

typedef unsigned short u16;
typedef unsigned int   u32;

typedef __attribute__((ext_vector_type(8)))  short bf16x8;
typedef __attribute__((ext_vector_type(4)))  float f32x4;
typedef __attribute__((ext_vector_type(16))) float f32x16;

#define B_  32
#define S_  1024
#define NH_ 512
#define G4_ 2048   // 4*NH
#define SC_NWG 8   // scan workgroups (8 waves each = 64 waves total)

__device__ __forceinline__ float bf2f(u16 h) {
    return __uint_as_float(((u32)h) << 16);
}
__device__ __forceinline__ u16 f2bf(float f) {
    u32 u = __float_as_uint(f);
    return (u16)((u + 0x7fffu + ((u >> 16) & 1u)) >> 16);
}
__device__ __forceinline__ float fsig(float x) {
    return 1.0f / (1.0f + __expf(-x));
}
__device__ __forceinline__ float ftanh(float x) {
    return 1.0f - 2.0f / (__expf(2.0f * x) + 1.0f);
}

// ---------------- fp32 -> bf16 elementwise convert (vectorized x4) ----------
__global__ void cvt_bf16_kernel(const float* __restrict__ in, u16* __restrict__ out, int n4) {
    int i = blockIdx.x * blockDim.x + threadIdx.x;
    if (i >= n4) return;
    f32x4 v = ((const f32x4*)in)[i];
    unsigned long long pk =
        (unsigned long long)f2bf(v[0]) |
        ((unsigned long long)f2bf(v[1]) << 16) |
        ((unsigned long long)f2bf(v[2]) << 32) |
        ((unsigned long long)f2bf(v[3]) << 48);
    ((unsigned long long*)out)[i] = pk;
}

// ---------------- fp32 [R][C] -> bf16 [C][R] transpose-convert --------------
__global__ void transpose_cvt_kernel(const float* __restrict__ in, u16* __restrict__ out,
                                     int R, int C) {
    __shared__ float tile[32][33];
    int bx = blockIdx.x, by = blockIdx.y;
    int tx = threadIdx.x & 31, ty = threadIdx.x >> 5;
    #pragma unroll
    for (int i = 0; i < 4; i++) {
        int r = by * 32 + ty + i * 8;
        tile[ty + i * 8][tx] = in[(size_t)r * C + bx * 32 + tx];
    }
    __syncthreads();
    #pragma unroll
    for (int i = 0; i < 4; i++) {
        int c = bx * 32 + ty + i * 8;
        out[(size_t)c * R + by * 32 + tx] = f2bf(tile[tx][ty + i * 8]);
    }
}

// ---------------- generic bf16 MFMA GEMM: C = A @ BT^T + bias ---------------
// A [M][K] bf16 row-major, BT [N][K] bf16, bias [N] f32.
// out_bf16: 1 -> store bf16, 0 -> store f32.
// tb_permute: 1 -> store row (m&1023)*32 + (m>>10)   ([b][t] -> [t][b] remap)
__global__ __launch_bounds__(256) void gemm_bf16_kernel(
    const u16* __restrict__ A, const u16* __restrict__ BT,
    const float* __restrict__ bias, void* __restrict__ Cp,
    int M, int N, int K, int out_bf16, int tb_permute)
{
    __shared__ u16 Al[128][40];
    __shared__ u16 Bl[128][40];
    int nbm = M >> 7;
    int bm = blockIdx.x % nbm, bn = blockIdx.x / nbm;
    int tid = threadIdx.x, lane = tid & 63, wave = tid >> 6;
    int wr = wave >> 1, wc = wave & 1;
    f32x4 acc[4][4];
    #pragma unroll
    for (int i = 0; i < 4; i++)
        #pragma unroll
        for (int j = 0; j < 4; j++)
            acc[i][j] = (f32x4){0.f, 0.f, 0.f, 0.f};
    int fr  = lane & 15;
    int kof = (lane >> 4) << 3;

    for (int k0 = 0; k0 < K; k0 += 32) {
        __syncthreads();
        #pragma unroll
        for (int i = 0; i < 2; i++) {
            int chunk = i * 256 + tid;
            int r = chunk >> 2, c = (chunk & 3) << 3;
            *(bf16x8*)&Al[r][c] = *(const bf16x8*)&A[(size_t)(bm * 128 + r) * K + k0 + c];
            *(bf16x8*)&Bl[r][c] = *(const bf16x8*)&BT[(size_t)(bn * 128 + r) * K + k0 + c];
        }
        __syncthreads();
        bf16x8 af[4], bfr[4];
        #pragma unroll
        for (int mi = 0; mi < 4; mi++)
            af[mi] = *(const bf16x8*)&Al[wr * 64 + mi * 16 + fr][kof];
        #pragma unroll
        for (int ni = 0; ni < 4; ni++)
            bfr[ni] = *(const bf16x8*)&Bl[wc * 64 + ni * 16 + fr][kof];
        #pragma unroll
        for (int mi = 0; mi < 4; mi++)
            #pragma unroll
            for (int ni = 0; ni < 4; ni++)
                acc[mi][ni] = __builtin_amdgcn_mfma_f32_16x16x32_bf16(af[mi], bfr[ni], acc[mi][ni], 0, 0, 0);
    }
    int rq = lane >> 4;
    #pragma unroll
    for (int mi = 0; mi < 4; mi++) {
        #pragma unroll
        for (int ni = 0; ni < 4; ni++) {
            int n = bn * 128 + wc * 64 + ni * 16 + fr;
            float bv = bias ? bias[n] : 0.f;
            #pragma unroll
            for (int r = 0; r < 4; r++) {
                int m = bm * 128 + wr * 64 + mi * 16 + rq * 4 + r;
                float v = acc[mi][ni][r] + bv;
                size_t row = tb_permute ? ((size_t)(m & 1023) * 32 + (m >> 10)) : (size_t)m;
                if (out_bf16) ((u16*)Cp)[row * N + n] = f2bf(v);
                else          ((float*)Cp)[row * N + n] = v;
            }
        }
    }
}

// ---------------- LSTM scan: 8 persistent WGs x 8 waves ---------------------
// Wave w of WG g acts as "wg64 = g*8+w", owning hidden units [wg64*8, +8).
// Cross-WG h exchange + flags go through L3 via system-scope (sc0 sc1)
// loads/stores -- no L2 flush/invalidate fences anywhere.
// Protocol: end of step t each WG writes its h(t+1) slice (sc stores),
// vmcnt(0), syncthreads, tid0 sc-stores flags[wg]=t+1. Step t begins by
// polling all 8 flags >= t, which transitively guarantees every WG finished
// its step t-1 reads (flag is written after that WG's end-of-step barrier).
__global__ __launch_bounds__(512, 1) void lstm_scan_kernel(
    const u16* __restrict__ xw,    // [S][B][4H] bf16 (time-major!)
    const u16* __restrict__ UT,    // [4H][NH] bf16
    u16* __restrict__ hseq,        // [B][S][NH] bf16
    u16* __restrict__ hbuf,        // [2][B][NH] bf16
    u32* __restrict__ flags)       // [SC_NWG]
{
    __shared__ u16 h_lds[32][520];      // [batch][k], +8 u16 pad (verified 0-conflict)
    __shared__ float gl[8][32][32];     // per-wave gate exchange

    const int tid  = threadIdx.x;
    const int wave = tid >> 6, lane = tid & 63;
    const int wg64 = (int)blockIdx.x * 8 + wave;
    const int col  = lane & 31, half = lane >> 5;
    const int u_loc = col >> 2, g_loc = col & 3;
    const int ucol  = g_loc * 512 + wg64 * 8 + u_loc;

    // persistent U B-fragments: 128 VGPRs/lane, zero weight traffic in the loop
    bf16x8 ufrag[32];
    #pragma unroll
    for (int kk = 0; kk < 32; kk++)
        ufrag[kk] = *(const bf16x8*)&UT[(size_t)ucol * 512 + kk * 16 + half * 8];

    float cst[4] = {0.f, 0.f, 0.f, 0.f};

    // h(0) = 0: zero LDS once (t=0 skips poll+stage)
    {
        bf16x8 z = (bf16x8){0, 0, 0, 0, 0, 0, 0, 0};
        bf16x8* hf = (bf16x8*)&h_lds[0][0];
        for (int i = tid; i < 2080; i += 512) hf[i] = z;
    }

    const int sb_b  = tid >> 4;   // staging: row (batch) 0..31
    const int sb_ic = tid & 15;   // 16 lanes cover one 1KB row, 16B-strided

    for (int t = 0; t < 1024; t++) {
        // ---- xw prefetch for this step (regular cached loads, dense slab) ----
        u16 xwu[16];
        #pragma unroll
        for (int r = 0; r < 16; r++) {
            int b = (r & 3) + ((r >> 2) << 3) + (half << 2);   // MFMA D-row map
            xwu[r] = xw[((size_t)t * 32 + b) * G4_ + ucol];
        }

        if (t > 0) {
            // ---- poll producer flags (one parallel coherent load, fan-in 8) ----
            const u32* fp = flags + (lane & 7);
            while (1) {
                u32 f;
                asm volatile("global_load_dword %0, %1, off sc0 sc1\n\t"
                             "s_waitcnt vmcnt(0)"
                             : "=v"(f) : "v"(fp) : "memory");
                if (__all((int)(f >= (u32)t))) break;
            }
            // ---- stage h(t): 32KB via system-scope dwordx4 loads -> LDS ----
            const char* sbase = (const char*)(hbuf + ((size_t)(t & 1) << 14))
                                + sb_b * 1024 + sb_ic * 16;
            f32x4 r0, r1, r2, r3;
            asm volatile(
                "global_load_dwordx4 %0, %4, off sc0 sc1\n\t"
                "global_load_dwordx4 %1, %5, off sc0 sc1\n\t"
                "global_load_dwordx4 %2, %6, off sc0 sc1\n\t"
                "global_load_dwordx4 %3, %7, off sc0 sc1\n\t"
                "s_waitcnt vmcnt(0)"
                : "=&v"(r0), "=&v"(r1), "=&v"(r2), "=&v"(r3)
                : "v"(sbase), "v"(sbase + 256), "v"(sbase + 512), "v"(sbase + 768)
                : "memory");
            __builtin_amdgcn_sched_barrier(0);
            u16* d = &h_lds[sb_b][sb_ic * 8];
            *(f32x4*)(d)       = r0;
            *(f32x4*)(d + 128) = r1;
            *(f32x4*)(d + 256) = r2;
            *(f32x4*)(d + 384) = r3;
        }
        __syncthreads();

        // ---- gates = h @ Uslice (32 MFMA, ~107ns of matrix work) ----
        f32x16 acc = {0,0,0,0, 0,0,0,0, 0,0,0,0, 0,0,0,0};
        #pragma unroll
        for (int kk = 0; kk < 32; kk++) {
            bf16x8 af = *(const bf16x8*)&h_lds[col][kk * 16 + half * 8];
            acc = __builtin_amdgcn_mfma_f32_32x32x16_bf16(af, ufrag[kk], acc, 0, 0, 0);
        }

        // ---- gate exchange (wave-local LDS; lgkmcnt ordering, no barrier) ----
        #pragma unroll
        for (int r = 0; r < 16; r++) {
            int b = (r & 3) + ((r >> 2) << 3) + (half << 2);
            gl[wave][b][col] = acc[r] + bf2f(xwu[r]);
        }

        // ---- cell update: each lane owns 4 (batch,unit) pairs ----
        u16* hb_out = hbuf + ((size_t)((t + 1) & 1) << 14);
        #pragma unroll
        for (int i = 0; i < 4; i++) {
            int p = (i << 6) + lane, b = p >> 3, u = p & 7;
            f32x4 g4 = *(const f32x4*)&gl[wave][b][u << 2];   // i,f,g,o
            float si = fsig(g4[0]), sf = fsig(g4[1]);
            float sg = ftanh(g4[2]), so = fsig(g4[3]);
            float c = sf * cst[i] + si * sg;
            cst[i] = c;
            float h = so * ftanh(c);
            u16 hv = f2bf(h);
            int j = (wg64 << 3) + u;
            hseq[((size_t)b * S_ + t) * NH_ + j] = hv;        // cached; read post-kernel
            u16* hp = hb_out + b * NH_ + j;
            u32 hw = hv;
            asm volatile("global_store_short %0, %1, off sc0 sc1"
                         :: "v"(hp), "v"(hw) : "memory");
        }
        // drain our sc stores, then WG-wide barrier, then publish flag
        asm volatile("s_waitcnt vmcnt(0)" ::: "memory");
        __syncthreads();
        if (tid == 0) {
            u32 fv = (u32)(t + 1);
            u32* fq = flags + blockIdx.x;
            asm volatile("global_store_dword %0, %1, off sc0 sc1"
                         :: "v"(fq), "v"(fv) : "memory");
        }
    }
}

extern "C" void kernel_launch(void* const* d_in, const int* in_sizes, int n_in,
                              void* d_out, int out_size, void* d_ws, size_t ws_size,
                              hipStream_t stream) {
    const float* x        = (const float*)d_in[0];
    const float* W        = (const float*)d_in[1];
    const float* U        = (const float*)d_in[2];
    const float* hid_bias = (const float*)d_in[3];
    const float* V        = (const float*)d_in[4];
    const float* out_bias = (const float*)d_in[5];

    char* ws = (char*)d_ws;
    size_t off = 0;
    auto carve = [&](size_t bytes) -> void* {
        void* p = ws + off;
        off += (bytes + 255) & ~(size_t)255;
        return p;
    };
    u16* xw    = (u16*)carve((size_t)B_ * S_ * G4_ * 2);   // 128 MB, [t][b][4H]
    u16* xbf   = (u16*)carve((size_t)B_ * S_ * NH_ * 2);   //  32 MB
    u16* hseq  = (u16*)carve((size_t)B_ * S_ * NH_ * 2);   //  32 MB
    u16* WT    = (u16*)carve((size_t)G4_ * NH_ * 2);       //   2 MB
    u16* UT    = (u16*)carve((size_t)G4_ * NH_ * 2);       //   2 MB
    u16* VT    = (u16*)carve((size_t)NH_ * NH_ * 2);       // 512 KB
    u16* hbuf  = (u16*)carve((size_t)2 * B_ * NH_ * 2);    //  64 KB
    u32* flags = (u32*)carve(256);

    hipMemsetAsync(flags, 0, 256, stream);

    int n4 = B_ * S_ * NH_ / 4;
    cvt_bf16_kernel<<<(n4 + 255) / 256, 256, 0, stream>>>(x, xbf, n4);
    transpose_cvt_kernel<<<dim3(G4_ / 32, NH_ / 32), 256, 0, stream>>>(W, WT, NH_, G4_);
    transpose_cvt_kernel<<<dim3(G4_ / 32, NH_ / 32), 256, 0, stream>>>(U, UT, NH_, G4_);
    transpose_cvt_kernel<<<dim3(NH_ / 32, NH_ / 32), 256, 0, stream>>>(V, VT, NH_, NH_);

    // xW + hid_bias -> bf16, stored time-major [t][b][4H]
    gemm_bf16_kernel<<<4096, 256, 0, stream>>>(xbf, WT, hid_bias, xw,
                                               B_ * S_, G4_, NH_, 1, 1);
    // sequential LSTM scan
    lstm_scan_kernel<<<SC_NWG, 512, 0, stream>>>(xw, UT, hseq, hbuf, flags);
    // out = hseq @ V + out_bias -> f32
    gemm_bf16_kernel<<<1024, 256, 0, stream>>>(hseq, VT, out_bias, d_out,
                                               B_ * S_, NH_, NH_, 0, 0);
}